// Round 4
// baseline (312.164 us; speedup 1.0000x reference)
//
#include <hip/hip_runtime.h>
#include <hip/hip_bf16.h>

#define N_ATOMS 512
#define CDIM 64
#define NSIG 16384
#define KS 4
#define NBINS 33

// ws layout (floats):
//   [0      , 32768 ) Dn   (row-major [c][n])
//   [32768  , 65536 ) DnT  (row-major [n][c])
//   [65536  , 327680) G    [n][n]
//   [327680 ]         loss acc
//   [327684 , +8388608) h_bar [s][n]   (fast path only)
#define WS_DN   0
#define WS_DNT  32768
#define WS_G    65536
#define WS_ACC  327680
#define WS_HBAR 327684
#define WS_FAST_FLOATS (WS_HBAR + NSIG * N_ATOMS)

__global__ void k_normalize(const float* __restrict__ dict,
                            float* __restrict__ Dn, float* __restrict__ DnT,
                            float* __restrict__ acc) {
    const int n = blockIdx.x;    // atom/column
    const int c = threadIdx.x;   // channel/row (64 threads = 1 wave)
    if (n == 0 && c == 0) *acc = 0.f;
    float v = dict[c * N_ATOMS + n];
    float sq = v * v;
    #pragma unroll
    for (int off = 32; off > 0; off >>= 1) sq += __shfl_down(sq, off);
    sq = __shfl(sq, 0);
    float m = fmaxf(sqrtf(sq), 1e-10f);
    float r = v / m;             // division to match reference exactly
    Dn[c * N_ATOMS + n] = r;
    DnT[n * CDIM + c]  = r;      // coalesced write (c contiguous)
}

__global__ void k_gram(const float* __restrict__ Dn, float* __restrict__ G) {
    __shared__ float sc[CDIM];
    const int i = blockIdx.x;
    const int t = threadIdx.x;
    if (t < CDIM) sc[t] = Dn[t * N_ATOMS + i];
    __syncthreads();
    for (int j = t; j < N_ATOMS; j += 256) {
        float a = 0.f;
        #pragma unroll
        for (int c = 0; c < CDIM; c++) a = fmaf(sc[c], Dn[c * N_ATOMS + j], a);
        G[i * N_ATOMS + j] = a;
    }
}

// h_bar = X^T * Dn ; block tile = 64 signals x 128 atoms, K=64 in one pass.
// Thread tile = 4 signals x 8 atoms. Accumulation order: k ascending (matches
// the previously-passing per-wave fmaf chain).
__global__ __launch_bounds__(256) void k_hbar(const float* __restrict__ z,
                                              const float* __restrict__ Dn,
                                              float* __restrict__ hbar) {
    __shared__ float Xs[64][64];     // [k][s_local]
    __shared__ float Dns[64][128];   // [k][n_local]
    const int t = threadIdx.x;
    const int bs = blockIdx.x >> 2;
    const int bn = blockIdx.x & 3;
    const int s_base = bs * 64;
    const int b = s_base >> 10;
    const int hw_base = s_base & 1023;
    const int n_base = bn * 128;

    {   // stage X tile: for fixed k, s is contiguous in z
        const int f = (t & 15) * 4;      // float offset within 64-wide row
        const int k0 = t >> 4;           // 16 rows per pass
        #pragma unroll
        for (int p = 0; p < 4; p++) {
            const int k = k0 + p * 16;
            float4 v = *(const float4*)(z + (b * CDIM + k) * 1024 + hw_base + f);
            *(float4*)(&Xs[k][f]) = v;
        }
    }
    {   // stage Dn tile
        const int f = (t & 31) * 4;      // float offset within 128-wide row
        const int k0 = t >> 5;           // 8 rows per pass
        #pragma unroll
        for (int p = 0; p < 8; p++) {
            const int k = k0 + p * 8;
            float4 v = *(const float4*)(Dn + k * N_ATOMS + n_base + f);
            *(float4*)(&Dns[k][f]) = v;
        }
    }
    __syncthreads();

    const int tn = (t & 15) * 8;         // 8 atoms per thread
    const int ts = (t >> 4) * 4;         // 4 signals per thread
    float a[4][8];
    #pragma unroll
    for (int i = 0; i < 4; i++)
        #pragma unroll
        for (int j = 0; j < 8; j++) a[i][j] = 0.f;

    for (int k = 0; k < 64; k++) {
        float4 xv = *(const float4*)(&Xs[k][ts]);
        float4 d0 = *(const float4*)(&Dns[k][tn]);
        float4 d1 = *(const float4*)(&Dns[k][tn + 4]);
        const float xs[4] = {xv.x, xv.y, xv.z, xv.w};
        const float dn[8] = {d0.x, d0.y, d0.z, d0.w, d1.x, d1.y, d1.z, d1.w};
        #pragma unroll
        for (int i = 0; i < 4; i++)
            #pragma unroll
            for (int j = 0; j < 8; j++) a[i][j] = fmaf(xs[i], dn[j], a[i][j]);
    }

    #pragma unroll
    for (int i = 0; i < 4; i++) {
        float* dst = hbar + (size_t)(s_base + ts + i) * N_ATOMS + n_base + tn;
        *(float4*)(dst)     = make_float4(a[i][0], a[i][1], a[i][2], a[i][3]);
        *(float4*)(dst + 4) = make_float4(a[i][4], a[i][5], a[i][6], a[i][7]);
    }
}

__device__ __forceinline__ float pick8(const float* a, int s) {
    switch (s) {
        case 0: return a[0]; case 1: return a[1]; case 2: return a[2]; case 3: return a[3];
        case 4: return a[4]; case 5: return a[5]; case 6: return a[6]; default: return a[7];
    }
}

// Shared OMP body given hb[8] already in registers (lane owns atoms lane*8+j).
__device__ __forceinline__ void omp_body(
    const float hb[8], const float* __restrict__ G, int lane,
    int I[KS], float coef[KS])
{
    float h[8];
    #pragma unroll
    for (int j = 0; j < 8; j++) h[j] = hb[j];

    unsigned sel = 0;
    float L[KS][KS];
    float hsel[KS];
    L[0][0] = 1.f;

    #pragma unroll
    for (int k = 0; k < KS; k++) {
        // argmax of |where(selected, 0, h)|, first-max tie-break (lowest atom idx)
        float bv = -1.f; int bn = N_ATOMS;
        #pragma unroll
        for (int j = 0; j < 8; j++) {
            float v = (sel & (1u << j)) ? 0.f : fabsf(h[j]);
            if (v > bv) { bv = v; bn = lane * 8 + j; }
        }
        #pragma unroll
        for (int off = 32; off > 0; off >>= 1) {
            float ov = __shfl_down(bv, off);
            int   on = __shfl_down(bn, off);
            if (ov > bv || (ov == bv && on < bn)) { bv = ov; bn = on; }
        }
        const int idx = __shfl(bn, 0);
        if ((idx >> 3) == lane) sel |= 1u << (idx & 7);

        if (k > 0) {
            float w[KS - 1];
            for (int i2 = 0; i2 < k; i2++) {
                float t = G[I[i2] * N_ATOMS + idx];
                for (int j2 = 0; j2 < i2; j2++) t -= L[i2][j2] * w[j2];
                w[i2] = t / L[i2][i2];
            }
            float ssum = 0.f;
            for (int j2 = 0; j2 < k; j2++) ssum += w[j2] * w[j2];
            float corner = sqrtf(fmaxf(1.f - ssum, 1e-12f));
            for (int j2 = 0; j2 < k; j2++) L[k][j2] = w[j2];
            L[k][k] = corner;
        }
        I[k] = idx;
        hsel[k] = __shfl(pick8(hb, idx & 7), idx >> 3);

        float y[KS];
        for (int i2 = 0; i2 <= k; i2++) {
            float t = hsel[i2];
            for (int j2 = 0; j2 < i2; j2++) t -= L[i2][j2] * y[j2];
            y[i2] = t / L[i2][i2];
        }
        for (int i2 = k; i2 >= 0; i2--) {
            float t = y[i2];
            for (int j2 = i2 + 1; j2 <= k; j2++) t -= L[j2][i2] * coef[j2];
            coef[i2] = t / L[i2][i2];
        }

        if (k < KS - 1) {
            float a[8];
            #pragma unroll
            for (int j = 0; j < 8; j++) a[j] = 0.f;
            for (int m = 0; m <= k; m++) {
                const float4* gr = (const float4*)(G + I[m] * N_ATOMS + lane * 8);
                float4 g0 = gr[0], g1 = gr[1];
                float cm = coef[m];
                a[0] = fmaf(cm, g0.x, a[0]); a[1] = fmaf(cm, g0.y, a[1]);
                a[2] = fmaf(cm, g0.z, a[2]); a[3] = fmaf(cm, g0.w, a[3]);
                a[4] = fmaf(cm, g1.x, a[4]); a[5] = fmaf(cm, g1.y, a[5]);
                a[6] = fmaf(cm, g1.z, a[6]); a[7] = fmaf(cm, g1.w, a[7]);
            }
            #pragma unroll
            for (int j = 0; j < 8; j++) h[j] = hb[j] - a[j];
        }
    }
}

__device__ __forceinline__ void omp_epilogue(
    const int I[KS], const float coef[KS], const float* __restrict__ atomsT,
    int atomsT_ldc, float xch, int s, int lane,
    float* __restrict__ acc, float* __restrict__ out)
{
    const int b = s >> 10;
    const int hw = s & 1023;
    int tok[KS]; float cq[KS];
    #pragma unroll
    for (int j = 0; j < KS; j++) {
        float c2 = fminf(fmaxf(coef[j], -2.f), 2.f);
        float bf = (c2 + 2.f) / 4.f * 32.f;
        int bin = (int)rintf(bf);
        bin = bin < 0 ? 0 : (bin > 32 ? 32 : bin);
        cq[j] = -2.f + 0.125f * (float)bin;
        tok[j] = I[j] * NBINS + bin;
    }
    float zq = 0.f;
    #pragma unroll
    for (int j = 0; j < KS; j++)
        zq = fmaf(cq[j], atomsT[I[j] * atomsT_ldc + lane], zq);

    float diff = zq - xch;
    float zste = xch + (zq - xch);
    out[(b * CDIM + lane) * 1024 + hw] = zste;

    float sq = diff * diff;
    #pragma unroll
    for (int off = 32; off > 0; off >>= 1) sq += __shfl_down(sq, off);
    if (lane == 0) atomicAdd(acc, sq);

    if (lane < KS)
        out[NSIG * CDIM + 1 + s * KS + lane] = (float)tok[lane];
}

// Fast path: h_bar precomputed.
__global__ __launch_bounds__(256) void k_omp_sel(
    const float* __restrict__ z, const float* __restrict__ hbar,
    const float* __restrict__ DnT, const float* __restrict__ G,
    float* __restrict__ acc, float* __restrict__ out)
{
    const int wave = threadIdx.x >> 6;
    const int lane = threadIdx.x & 63;
    const int s = blockIdx.x * 4 + wave;
    const int b = s >> 10;
    const int hw = s & 1023;

    const float xch = z[(b * CDIM + lane) * 1024 + hw];

    const float4* hrow = (const float4*)(hbar + (size_t)s * N_ATOMS + lane * 8);
    float4 h0 = hrow[0], h1 = hrow[1];
    float hb[8] = {h0.x, h0.y, h0.z, h0.w, h1.x, h1.y, h1.z, h1.w};

    int I[KS]; float coef[KS];
    omp_body(hb, G, lane, I, coef);
    omp_epilogue(I, coef, DnT, CDIM, xch, s, lane, acc, out);
}

// Fallback path (round-3 structure): compute hb in-wave from Dn.
__global__ __launch_bounds__(256) void k_omp_full(
    const float* __restrict__ z, const float* __restrict__ Dn,
    const float* __restrict__ G, float* __restrict__ acc,
    float* __restrict__ out)
{
    const int wave = threadIdx.x >> 6;
    const int lane = threadIdx.x & 63;
    const int s = blockIdx.x * 4 + wave;
    const int b = s >> 10;
    const int hw = s & 1023;

    const float xch = z[(b * CDIM + lane) * 1024 + hw];

    float hb[8];
    #pragma unroll
    for (int j = 0; j < 8; j++) hb[j] = 0.f;
    for (int c = 0; c < CDIM; c++) {
        float xc = __shfl(xch, c);
        const float4* row = (const float4*)(Dn + c * N_ATOMS + lane * 8);
        float4 r0 = row[0], r1 = row[1];
        hb[0] = fmaf(r0.x, xc, hb[0]); hb[1] = fmaf(r0.y, xc, hb[1]);
        hb[2] = fmaf(r0.z, xc, hb[2]); hb[3] = fmaf(r0.w, xc, hb[3]);
        hb[4] = fmaf(r1.x, xc, hb[4]); hb[5] = fmaf(r1.y, xc, hb[5]);
        hb[6] = fmaf(r1.z, xc, hb[6]); hb[7] = fmaf(r1.w, xc, hb[7]);
    }

    int I[KS]; float coef[KS];
    omp_body(hb, G, lane, I, coef);

    // recon from Dn (row-major [c][n]) — same values as DnT
    int tok[KS]; float cq[KS];
    #pragma unroll
    for (int j = 0; j < KS; j++) {
        float c2 = fminf(fmaxf(coef[j], -2.f), 2.f);
        float bf = (c2 + 2.f) / 4.f * 32.f;
        int bin = (int)rintf(bf);
        bin = bin < 0 ? 0 : (bin > 32 ? 32 : bin);
        cq[j] = -2.f + 0.125f * (float)bin;
        tok[j] = I[j] * NBINS + bin;
    }
    float zq = 0.f;
    #pragma unroll
    for (int j = 0; j < KS; j++) zq = fmaf(cq[j], Dn[lane * N_ATOMS + I[j]], zq);

    float diff = zq - xch;
    float zste = xch + (zq - xch);
    out[(b * CDIM + lane) * 1024 + hw] = zste;

    float sq = diff * diff;
    #pragma unroll
    for (int off = 32; off > 0; off >>= 1) sq += __shfl_down(sq, off);
    if (lane == 0) atomicAdd(acc, sq);

    if (lane < KS)
        out[NSIG * CDIM + 1 + s * KS + lane] = (float)tok[lane];
}

__global__ void k_final(const float* __restrict__ acc, float* __restrict__ out) {
    float v = *acc / 1048576.f;
    out[NSIG * CDIM] = v + 0.25f * v;
}

extern "C" void kernel_launch(void* const* d_in, const int* in_sizes, int n_in,
                              void* d_out, int out_size, void* d_ws, size_t ws_size,
                              hipStream_t stream) {
    const float* z    = (const float*)d_in[0];
    const float* dict = (const float*)d_in[1];
    float* out  = (float*)d_out;
    float* w    = (float*)d_ws;
    float* Dn   = w + WS_DN;
    float* DnT  = w + WS_DNT;
    float* G    = w + WS_G;
    float* acc  = w + WS_ACC;
    float* hbar = w + WS_HBAR;

    const bool fast = ws_size >= (size_t)WS_FAST_FLOATS * sizeof(float);

    hipLaunchKernelGGL(k_normalize, dim3(N_ATOMS), dim3(CDIM), 0, stream, dict, Dn, DnT, acc);
    hipLaunchKernelGGL(k_gram,      dim3(N_ATOMS), dim3(256),  0, stream, Dn, G);
    if (fast) {
        hipLaunchKernelGGL(k_hbar,    dim3(NSIG / 64 * 4), dim3(256), 0, stream, z, Dn, hbar);
        hipLaunchKernelGGL(k_omp_sel, dim3(NSIG / 4), dim3(256), 0, stream, z, hbar, DnT, G, acc, out);
    } else {
        hipLaunchKernelGGL(k_omp_full, dim3(NSIG / 4), dim3(256), 0, stream, z, Dn, G, acc, out);
    }
    hipLaunchKernelGGL(k_final, dim3(1), dim3(1), 0, stream, acc, out);
}

// Round 5
// 123.985 us; speedup vs baseline: 2.5178x; 2.5178x over previous
//
#include <hip/hip_runtime.h>
#include <hip/hip_bf16.h>

#define N_ATOMS 512
#define CDIM 64
#define NSIG 16384
#define KS 4
#define NBINS 33

// ws layout (floats):
//   [0      , 32768 ) Dn   (row-major [c][n])
//   [32768  , 65536 ) DnT  (row-major [n][c])
//   [65536  , 327680) G    [n][n]
//   [327680 , 344064) per-wave loss partials [s]
//   [344064 , +8388608) h_bar [s][n]   (fast path only)
#define WS_DN   0
#define WS_DNT  32768
#define WS_G    65536
#define WS_PART 327680
#define WS_HBAR (327680 + NSIG)
#define WS_FAST_FLOATS (WS_HBAR + NSIG * N_ATOMS)

__global__ void k_normalize(const float* __restrict__ dict,
                            float* __restrict__ Dn, float* __restrict__ DnT) {
    const int n = blockIdx.x;    // atom/column
    const int c = threadIdx.x;   // channel/row (64 threads = 1 wave)
    float v = dict[c * N_ATOMS + n];
    float sq = v * v;
    #pragma unroll
    for (int off = 32; off > 0; off >>= 1) sq += __shfl_down(sq, off);
    sq = __shfl(sq, 0);
    float m = fmaxf(sqrtf(sq), 1e-10f);
    float r = v / m;             // division to match reference exactly
    Dn[c * N_ATOMS + n] = r;
    DnT[n * CDIM + c]  = r;      // coalesced write (c contiguous)
}

__global__ void k_gram(const float* __restrict__ Dn, float* __restrict__ G) {
    __shared__ float sc[CDIM];
    const int i = blockIdx.x;
    const int t = threadIdx.x;
    if (t < CDIM) sc[t] = Dn[t * N_ATOMS + i];
    __syncthreads();
    for (int j = t; j < N_ATOMS; j += 256) {
        float a = 0.f;
        #pragma unroll
        for (int c = 0; c < CDIM; c++) a = fmaf(sc[c], Dn[c * N_ATOMS + j], a);
        G[i * N_ATOMS + j] = a;
    }
}

// h_bar = X^T * Dn ; block tile = 64 signals x 128 atoms, K=64 in one pass.
__global__ __launch_bounds__(256) void k_hbar(const float* __restrict__ z,
                                              const float* __restrict__ Dn,
                                              float* __restrict__ hbar) {
    __shared__ float Xs[64][64];     // [k][s_local]
    __shared__ float Dns[64][128];   // [k][n_local]
    const int t = threadIdx.x;
    const int bs = blockIdx.x >> 2;
    const int bn = blockIdx.x & 3;
    const int s_base = bs * 64;
    const int b = s_base >> 10;
    const int hw_base = s_base & 1023;
    const int n_base = bn * 128;

    {   // stage X tile: for fixed k, s is contiguous in z
        const int f = (t & 15) * 4;
        const int k0 = t >> 4;
        #pragma unroll
        for (int p = 0; p < 4; p++) {
            const int k = k0 + p * 16;
            float4 v = *(const float4*)(z + (b * CDIM + k) * 1024 + hw_base + f);
            *(float4*)(&Xs[k][f]) = v;
        }
    }
    {   // stage Dn tile
        const int f = (t & 31) * 4;
        const int k0 = t >> 5;
        #pragma unroll
        for (int p = 0; p < 8; p++) {
            const int k = k0 + p * 8;
            float4 v = *(const float4*)(Dn + k * N_ATOMS + n_base + f);
            *(float4*)(&Dns[k][f]) = v;
        }
    }
    __syncthreads();

    const int tn = (t & 15) * 8;
    const int ts = (t >> 4) * 4;
    float a[4][8];
    #pragma unroll
    for (int i = 0; i < 4; i++)
        #pragma unroll
        for (int j = 0; j < 8; j++) a[i][j] = 0.f;

    for (int k = 0; k < 64; k++) {
        float4 xv = *(const float4*)(&Xs[k][ts]);
        float4 d0 = *(const float4*)(&Dns[k][tn]);
        float4 d1 = *(const float4*)(&Dns[k][tn + 4]);
        const float xs[4] = {xv.x, xv.y, xv.z, xv.w};
        const float dn[8] = {d0.x, d0.y, d0.z, d0.w, d1.x, d1.y, d1.z, d1.w};
        #pragma unroll
        for (int i = 0; i < 4; i++)
            #pragma unroll
            for (int j = 0; j < 8; j++) a[i][j] = fmaf(xs[i], dn[j], a[i][j]);
    }

    #pragma unroll
    for (int i = 0; i < 4; i++) {
        float* dst = hbar + (size_t)(s_base + ts + i) * N_ATOMS + n_base + tn;
        *(float4*)(dst)     = make_float4(a[i][0], a[i][1], a[i][2], a[i][3]);
        *(float4*)(dst + 4) = make_float4(a[i][4], a[i][5], a[i][6], a[i][7]);
    }
}

__device__ __forceinline__ float pick8(const float* a, int s) {
    switch (s) {
        case 0: return a[0]; case 1: return a[1]; case 2: return a[2]; case 3: return a[3];
        case 4: return a[4]; case 5: return a[5]; case 6: return a[6]; default: return a[7];
    }
}

__device__ __forceinline__ void omp_body(
    const float hb[8], const float* __restrict__ G, int lane,
    int I[KS], float coef[KS])
{
    float h[8];
    #pragma unroll
    for (int j = 0; j < 8; j++) h[j] = hb[j];

    unsigned sel = 0;
    float L[KS][KS];
    float hsel[KS];
    L[0][0] = 1.f;

    #pragma unroll
    for (int k = 0; k < KS; k++) {
        float bv = -1.f; int bn = N_ATOMS;
        #pragma unroll
        for (int j = 0; j < 8; j++) {
            float v = (sel & (1u << j)) ? 0.f : fabsf(h[j]);
            if (v > bv) { bv = v; bn = lane * 8 + j; }
        }
        #pragma unroll
        for (int off = 32; off > 0; off >>= 1) {
            float ov = __shfl_down(bv, off);
            int   on = __shfl_down(bn, off);
            if (ov > bv || (ov == bv && on < bn)) { bv = ov; bn = on; }
        }
        const int idx = __shfl(bn, 0);
        if ((idx >> 3) == lane) sel |= 1u << (idx & 7);

        if (k > 0) {
            float w[KS - 1];
            for (int i2 = 0; i2 < k; i2++) {
                float t = G[I[i2] * N_ATOMS + idx];
                for (int j2 = 0; j2 < i2; j2++) t -= L[i2][j2] * w[j2];
                w[i2] = t / L[i2][i2];
            }
            float ssum = 0.f;
            for (int j2 = 0; j2 < k; j2++) ssum += w[j2] * w[j2];
            float corner = sqrtf(fmaxf(1.f - ssum, 1e-12f));
            for (int j2 = 0; j2 < k; j2++) L[k][j2] = w[j2];
            L[k][k] = corner;
        }
        I[k] = idx;
        hsel[k] = __shfl(pick8(hb, idx & 7), idx >> 3);

        float y[KS];
        for (int i2 = 0; i2 <= k; i2++) {
            float t = hsel[i2];
            for (int j2 = 0; j2 < i2; j2++) t -= L[i2][j2] * y[j2];
            y[i2] = t / L[i2][i2];
        }
        for (int i2 = k; i2 >= 0; i2--) {
            float t = y[i2];
            for (int j2 = i2 + 1; j2 <= k; j2++) t -= L[j2][i2] * coef[j2];
            coef[i2] = t / L[i2][i2];
        }

        if (k < KS - 1) {
            float a[8];
            #pragma unroll
            for (int j = 0; j < 8; j++) a[j] = 0.f;
            for (int m = 0; m <= k; m++) {
                const float4* gr = (const float4*)(G + I[m] * N_ATOMS + lane * 8);
                float4 g0 = gr[0], g1 = gr[1];
                float cm = coef[m];
                a[0] = fmaf(cm, g0.x, a[0]); a[1] = fmaf(cm, g0.y, a[1]);
                a[2] = fmaf(cm, g0.z, a[2]); a[3] = fmaf(cm, g0.w, a[3]);
                a[4] = fmaf(cm, g1.x, a[4]); a[5] = fmaf(cm, g1.y, a[5]);
                a[6] = fmaf(cm, g1.z, a[6]); a[7] = fmaf(cm, g1.w, a[7]);
            }
            #pragma unroll
            for (int j = 0; j < 8; j++) h[j] = hb[j] - a[j];
        }
    }
}

__device__ __forceinline__ void omp_epilogue(
    const int I[KS], const float coef[KS], const float* __restrict__ atomsT,
    int atomsT_ldc, float xch, int s, int lane,
    float* __restrict__ part, float* __restrict__ out)
{
    const int b = s >> 10;
    const int hw = s & 1023;
    int tok[KS]; float cq[KS];
    #pragma unroll
    for (int j = 0; j < KS; j++) {
        float c2 = fminf(fmaxf(coef[j], -2.f), 2.f);
        float bf = (c2 + 2.f) / 4.f * 32.f;
        int bin = (int)rintf(bf);
        bin = bin < 0 ? 0 : (bin > 32 ? 32 : bin);
        cq[j] = -2.f + 0.125f * (float)bin;
        tok[j] = I[j] * NBINS + bin;
    }
    float zq = 0.f;
    #pragma unroll
    for (int j = 0; j < KS; j++)
        zq = fmaf(cq[j], atomsT[I[j] * atomsT_ldc + lane], zq);

    float diff = zq - xch;
    float zste = xch + (zq - xch);
    out[(b * CDIM + lane) * 1024 + hw] = zste;

    float sq = diff * diff;
    #pragma unroll
    for (int off = 32; off > 0; off >>= 1) sq += __shfl_down(sq, off);
    if (lane == 0) part[s] = sq;          // no atomics: per-wave partial

    if (lane < KS)
        out[NSIG * CDIM + 1 + s * KS + lane] = (float)tok[lane];
}

// Fast path: h_bar precomputed.
__global__ __launch_bounds__(256) void k_omp_sel(
    const float* __restrict__ z, const float* __restrict__ hbar,
    const float* __restrict__ DnT, const float* __restrict__ G,
    float* __restrict__ part, float* __restrict__ out)
{
    const int wave = threadIdx.x >> 6;
    const int lane = threadIdx.x & 63;
    const int s = blockIdx.x * 4 + wave;
    const int b = s >> 10;
    const int hw = s & 1023;

    const float xch = z[(b * CDIM + lane) * 1024 + hw];

    const float4* hrow = (const float4*)(hbar + (size_t)s * N_ATOMS + lane * 8);
    float4 h0 = hrow[0], h1 = hrow[1];
    float hb[8] = {h0.x, h0.y, h0.z, h0.w, h1.x, h1.y, h1.z, h1.w};

    int I[KS]; float coef[KS];
    omp_body(hb, G, lane, I, coef);
    omp_epilogue(I, coef, DnT, CDIM, xch, s, lane, part, out);
}

// Fallback path: compute hb in-wave from Dn.
__global__ __launch_bounds__(256) void k_omp_full(
    const float* __restrict__ z, const float* __restrict__ Dn,
    const float* __restrict__ DnT, const float* __restrict__ G,
    float* __restrict__ part, float* __restrict__ out)
{
    const int wave = threadIdx.x >> 6;
    const int lane = threadIdx.x & 63;
    const int s = blockIdx.x * 4 + wave;
    const int b = s >> 10;
    const int hw = s & 1023;

    const float xch = z[(b * CDIM + lane) * 1024 + hw];

    float hb[8];
    #pragma unroll
    for (int j = 0; j < 8; j++) hb[j] = 0.f;
    for (int c = 0; c < CDIM; c++) {
        float xc = __shfl(xch, c);
        const float4* row = (const float4*)(Dn + c * N_ATOMS + lane * 8);
        float4 r0 = row[0], r1 = row[1];
        hb[0] = fmaf(r0.x, xc, hb[0]); hb[1] = fmaf(r0.y, xc, hb[1]);
        hb[2] = fmaf(r0.z, xc, hb[2]); hb[3] = fmaf(r0.w, xc, hb[3]);
        hb[4] = fmaf(r1.x, xc, hb[4]); hb[5] = fmaf(r1.y, xc, hb[5]);
        hb[6] = fmaf(r1.z, xc, hb[6]); hb[7] = fmaf(r1.w, xc, hb[7]);
    }

    int I[KS]; float coef[KS];
    omp_body(hb, G, lane, I, coef);
    omp_epilogue(I, coef, DnT, CDIM, xch, s, lane, part, out);
}

__global__ __launch_bounds__(256) void k_final(const float* __restrict__ part,
                                               float* __restrict__ out) {
    __shared__ float red[4];
    const int t = threadIdx.x;
    float sum = 0.f;
    const float4* p4 = (const float4*)part;
    for (int i = t; i < NSIG / 4; i += 256) {
        float4 v = p4[i];
        sum += v.x + v.y + v.z + v.w;
    }
    #pragma unroll
    for (int off = 32; off > 0; off >>= 1) sum += __shfl_down(sum, off);
    if ((t & 63) == 0) red[t >> 6] = sum;
    __syncthreads();
    if (t == 0) {
        float v = (red[0] + red[1] + red[2] + red[3]) / 1048576.f;
        out[NSIG * CDIM] = v + 0.25f * v;
    }
}

extern "C" void kernel_launch(void* const* d_in, const int* in_sizes, int n_in,
                              void* d_out, int out_size, void* d_ws, size_t ws_size,
                              hipStream_t stream) {
    const float* z    = (const float*)d_in[0];
    const float* dict = (const float*)d_in[1];
    float* out  = (float*)d_out;
    float* w    = (float*)d_ws;
    float* Dn   = w + WS_DN;
    float* DnT  = w + WS_DNT;
    float* G    = w + WS_G;
    float* part = w + WS_PART;
    float* hbar = w + WS_HBAR;

    const bool fast = ws_size >= (size_t)WS_FAST_FLOATS * sizeof(float);

    hipLaunchKernelGGL(k_normalize, dim3(N_ATOMS), dim3(CDIM), 0, stream, dict, Dn, DnT);
    hipLaunchKernelGGL(k_gram,      dim3(N_ATOMS), dim3(256),  0, stream, Dn, G);
    if (fast) {
        hipLaunchKernelGGL(k_hbar,    dim3(NSIG / 64 * 4), dim3(256), 0, stream, z, Dn, hbar);
        hipLaunchKernelGGL(k_omp_sel, dim3(NSIG / 4), dim3(256), 0, stream, z, hbar, DnT, G, part, out);
    } else {
        hipLaunchKernelGGL(k_omp_full, dim3(NSIG / 4), dim3(256), 0, stream, z, Dn, DnT, G, part, out);
    }
    hipLaunchKernelGGL(k_final, dim3(1), dim3(256), 0, stream, part, out);
}